// Round 1
// baseline (630.247 us; speedup 1.0000x reference)
//
#include <hip/hip_runtime.h>
#include <cstdint>
#include <cstddef>

// Problem constants
#define H_   4096
#define D_   1024
#define A_   512
#define B_   4
#define LQ_  2048
#define TM_  1500
#define TMP_ 1536   // TM padded to multiple of 128
#define EPS_ 1e-5f

typedef __attribute__((ext_vector_type(8))) _Float16 half8;
typedef __attribute__((ext_vector_type(4))) _Float16 half4v;
typedef __attribute__((ext_vector_type(4))) float f32x4;

// ---------------------------------------------------------------- helpers
__device__ inline void gload_lds16(void* g, void* l) {
  // async global->LDS, 16B per lane; LDS dest = wave-uniform base + lane*16
  __builtin_amdgcn_global_load_lds((__attribute__((address_space(1))) void*)g,
                                   (__attribute__((address_space(3))) void*)l,
                                   16, 0, 0);
}

// ---------------------------------------------------------------- LN1: h_norm = LN(hidden) -> f16
__global__ __launch_bounds__(256) void ln1_kernel(
    const float* __restrict__ hidden_, const float* __restrict__ w,
    const float* __restrict__ bvec, _Float16* __restrict__ y_) {
  const int row = blockIdx.x;
  const float* x = hidden_ + (size_t)row * H_;
  _Float16* y = y_ + (size_t)row * H_;
  const int t = threadIdx.x;
  float4 v[4];
  float s = 0.f, ss = 0.f;
#pragma unroll
  for (int i = 0; i < 4; ++i) {
    v[i] = ((const float4*)x)[t + 256 * i];
    s  += v[i].x + v[i].y + v[i].z + v[i].w;
    ss += v[i].x * v[i].x + v[i].y * v[i].y + v[i].z * v[i].z + v[i].w * v[i].w;
  }
  __shared__ float red[2][4];
  const int lane = t & 63, wv = t >> 6;
#pragma unroll
  for (int off = 32; off; off >>= 1) { s += __shfl_down(s, off); ss += __shfl_down(ss, off); }
  if (lane == 0) { red[0][wv] = s; red[1][wv] = ss; }
  __syncthreads();
  s  = red[0][0] + red[0][1] + red[0][2] + red[0][3];
  ss = red[1][0] + red[1][1] + red[1][2] + red[1][3];
  const float mu = s * (1.f / H_);
  const float var = ss * (1.f / H_) - mu * mu;
  const float rstd = rsqrtf(var + EPS_);
#pragma unroll
  for (int i = 0; i < 4; ++i) {
    float4 wv4 = ((const float4*)w)[t + 256 * i];
    float4 bv4 = ((const float4*)bvec)[t + 256 * i];
    half4v o;
    o.x = (_Float16)((v[i].x - mu) * rstd * wv4.x + bv4.x);
    o.y = (_Float16)((v[i].y - mu) * rstd * wv4.y + bv4.y);
    o.z = (_Float16)((v[i].z - mu) * rstd * wv4.z + bv4.z);
    o.w = (_Float16)((v[i].w - mu) * rstd * wv4.w + bv4.w);
    ((half4v*)y)[t + 256 * i] = o;
  }
}

// ---------------------------------------------------------------- fp32 -> f16 convert (mem)
__global__ __launch_bounds__(256) void cvt_h_kernel(
    const float4* __restrict__ in, half4v* __restrict__ out, int n4) {
  for (int i = blockIdx.x * 256 + threadIdx.x; i < n4; i += gridDim.x * 256) {
    float4 f = in[i];
    half4v o;
    o.x = (_Float16)f.x; o.y = (_Float16)f.y; o.z = (_Float16)f.z; o.w = (_Float16)f.w;
    out[i] = o;
  }
}

// ---------------------------------------------------------------- transpose fp32 [R][C] -> f16 [C][R]
__global__ __launch_bounds__(256) void transpose_h_kernel(
    const float* __restrict__ in, _Float16* __restrict__ out, int R, int C) {
  __shared__ float tile[32][33];
  const int tx = threadIdx.x, ty = threadIdx.y;
  const int c0 = blockIdx.x * 32, r0 = blockIdx.y * 32;
#pragma unroll
  for (int i = 0; i < 32; i += 8)
    tile[ty + i][tx] = in[(size_t)(r0 + ty + i) * C + (c0 + tx)];
  __syncthreads();
#pragma unroll
  for (int i = 0; i < 32; i += 8)
    out[(size_t)(c0 + ty + i) * R + (r0 + tx)] = (_Float16)tile[tx][ty + i];
}

// ---------------------------------------------------------------- generic NT MFMA GEMM
// C[m][n] = scale * sum_k A[m][k] * Bt[n][k] + bias[n]
// A: [M][K] f16 (rows clamped to Mvalid for reads), Bt: [N][K] f16, C: f16.
// grid = (N/128, M/128, batches); block = 256 (4 waves).
template <int TRANS_OUT>
__global__ __launch_bounds__(256) void gemm_nt_kernel(
    const _Float16* __restrict__ Aall, size_t strideA,
    const _Float16* __restrict__ Btall, size_t strideB,
    const float* __restrict__ bias,
    _Float16* __restrict__ Call, size_t strideC,
    int Mvalid, int Kdim, int ldc, float scale) {
  __shared__ __align__(16) _Float16 As[4096];  // [128][32]
  __shared__ __align__(16) _Float16 Bs[4096];  // [128][32]
  const int tid = threadIdx.x;
  const int lane = tid & 63;
  const int wave = tid >> 6;
  const int m0 = blockIdx.y * 128;
  const int n0 = blockIdx.x * 128;
  const _Float16* Ab = Aall + (size_t)blockIdx.z * strideA;
  const _Float16* Bb = Btall + (size_t)blockIdx.z * strideB;

  f32x4 acc[4][4];
#pragma unroll
  for (int i = 0; i < 4; ++i)
#pragma unroll
    for (int j = 0; j < 4; ++j) acc[i][j] = (f32x4){0.f, 0.f, 0.f, 0.f};

  // staging: 128x32 f16 tile = 512 chunks of 16B; 256 threads x 2 chunks
  const _Float16* gA[2];
  const _Float16* gB[2];
  _Float16* lA[2];
  _Float16* lB[2];
#pragma unroll
  for (int i = 0; i < 2; ++i) {
    const int c = wave * 64 + lane + 256 * i;
    const int r = c >> 2;
    const int col = (c & 3) * 8;
    int ra = m0 + r;
    if (ra >= Mvalid) ra = Mvalid - 1;  // clamp (pad rows duplicate last valid row)
    gA[i] = Ab + (size_t)ra * Kdim + col;
    gB[i] = Bb + (size_t)(n0 + r) * Kdim + col;
    lA[i] = As + wave * 512 + i * 2048;  // wave-uniform LDS base
    lB[i] = Bs + wave * 512 + i * 2048;
  }

  const int wm = (wave >> 1) * 64;
  const int wn = (wave & 1) * 64;
  const int rsub = lane & 15;
  const int kq = (lane >> 4) * 8;

  const int nK = Kdim >> 5;
  for (int kt = 0; kt < nK; ++kt) {
    const int ko = kt * 32;
#pragma unroll
    for (int i = 0; i < 2; ++i) {
      gload_lds16((void*)(gA[i] + ko), (void*)lA[i]);
      gload_lds16((void*)(gB[i] + ko), (void*)lB[i]);
    }
    __syncthreads();  // compiler drains vmcnt before s_barrier
    half8 af[4], bfr[4];
#pragma unroll
    for (int x = 0; x < 4; ++x) {
      af[x]  = *(const half8*)&As[(wm + x * 16 + rsub) * 32 + kq];
      bfr[x] = *(const half8*)&Bs[(wn + x * 16 + rsub) * 32 + kq];
    }
#pragma unroll
    for (int mi = 0; mi < 4; ++mi)
#pragma unroll
      for (int ni = 0; ni < 4; ++ni)
        acc[mi][ni] = __builtin_amdgcn_mfma_f32_16x16x32_f16(af[mi], bfr[ni], acc[mi][ni], 0, 0, 0);
    __syncthreads();
  }

  _Float16* C = Call + (size_t)blockIdx.z * strideC;
  const int cn = n0 + wn + rsub;
  const int rm = m0 + wm + (lane >> 4) * 4;
#pragma unroll
  for (int ni = 0; ni < 4; ++ni) {
    const int n = cn + ni * 16;
    const float bi = bias ? bias[n] : 0.f;
#pragma unroll
    for (int mi = 0; mi < 4; ++mi) {
#pragma unroll
      for (int r = 0; r < 4; ++r) {
        const int m = rm + mi * 16 + r;
        const float v = acc[mi][ni][r] * scale + bi;
        const size_t idx = TRANS_OUT ? ((size_t)n * ldc + m) : ((size_t)m * ldc + n);
        C[idx] = (_Float16)v;
      }
    }
  }
}

// ---------------------------------------------------------------- softmax rows (in-place f16), pad cols -> 0
__global__ __launch_bounds__(256) void softmax_kernel(
    _Float16* __restrict__ scores, const unsigned char* __restrict__ mask) {
  const int row = blockIdx.x;          // B*LQ rows
  const int b = row >> 11;             // / LQ_
  _Float16* s = scores + (size_t)row * TMP_;
  const unsigned char* mk = mask + (size_t)b * TM_;
  const int t = threadIdx.x;
  float v[6];
#pragma unroll
  for (int i = 0; i < 6; ++i) {
    const int c = t + 256 * i;
    float x;
    if (c >= TM_) x = -INFINITY;                 // pad -> exactly zero weight
    else if (mk[c]) x = -1e30f;                  // reference mask semantics
    else x = (float)s[c];
    v[i] = x;
  }
  __shared__ float red[4];
  const int lane = t & 63, wv = t >> 6;
  float m = v[0];
#pragma unroll
  for (int i = 1; i < 6; ++i) m = fmaxf(m, v[i]);
#pragma unroll
  for (int off = 32; off; off >>= 1) m = fmaxf(m, __shfl_down(m, off));
  if (lane == 0) red[wv] = m;
  __syncthreads();
  m = fmaxf(fmaxf(red[0], red[1]), fmaxf(red[2], red[3]));
  float sum = 0.f;
#pragma unroll
  for (int i = 0; i < 6; ++i) { v[i] = __expf(v[i] - m); sum += v[i]; }
  __syncthreads();
#pragma unroll
  for (int off = 32; off; off >>= 1) sum += __shfl_down(sum, off);
  if (lane == 0) red[wv] = sum;
  __syncthreads();
  sum = red[0] + red[1] + red[2] + red[3];
  const float inv = 1.f / sum;
#pragma unroll
  for (int i = 0; i < 6; ++i) s[t + 256 * i] = (_Float16)(v[i] * inv);
}

// ---------------------------------------------------------------- LN2 + gate epilogue -> out (fp32)
__global__ __launch_bounds__(256) void ln2_gate_kernel(
    const float* __restrict__ hidden_, const _Float16* __restrict__ ctxh_,
    const float* __restrict__ w, const float* __restrict__ bvec,
    const float* __restrict__ gate_logit, float* __restrict__ out_) {
  const int row = blockIdx.x;
  const float* h = hidden_ + (size_t)row * H_;
  const _Float16* c = ctxh_ + (size_t)row * H_;
  float* o = out_ + (size_t)row * H_;
  const int t = threadIdx.x;
  float4 hv[4];
  float xv[16];
  float s = 0.f, ss = 0.f;
#pragma unroll
  for (int i = 0; i < 4; ++i) {
    hv[i] = ((const float4*)h)[t + 256 * i];
    half4v cv = ((const half4v*)c)[t + 256 * i];
    xv[4 * i + 0] = hv[i].x + (float)cv.x;
    xv[4 * i + 1] = hv[i].y + (float)cv.y;
    xv[4 * i + 2] = hv[i].z + (float)cv.z;
    xv[4 * i + 3] = hv[i].w + (float)cv.w;
    s  += xv[4 * i + 0] + xv[4 * i + 1] + xv[4 * i + 2] + xv[4 * i + 3];
    ss += xv[4 * i + 0] * xv[4 * i + 0] + xv[4 * i + 1] * xv[4 * i + 1] +
          xv[4 * i + 2] * xv[4 * i + 2] + xv[4 * i + 3] * xv[4 * i + 3];
  }
  __shared__ float red[2][4];
  const int lane = t & 63, wv = t >> 6;
#pragma unroll
  for (int off = 32; off; off >>= 1) { s += __shfl_down(s, off); ss += __shfl_down(ss, off); }
  if (lane == 0) { red[0][wv] = s; red[1][wv] = ss; }
  __syncthreads();
  s  = red[0][0] + red[0][1] + red[0][2] + red[0][3];
  ss = red[1][0] + red[1][1] + red[1][2] + red[1][3];
  const float mu = s * (1.f / H_);
  const float var = ss * (1.f / H_) - mu * mu;
  const float rstd = rsqrtf(var + EPS_);
  const float g = 1.f / (1.f + __expf(-gate_logit[0]));
#pragma unroll
  for (int i = 0; i < 4; ++i) {
    float4 wv4 = ((const float4*)w)[t + 256 * i];
    float4 bv4 = ((const float4*)bvec)[t + 256 * i];
    float4 ov;
    ov.x = hv[i].x + g * ((xv[4 * i + 0] - mu) * rstd * wv4.x + bv4.x - hv[i].x);
    ov.y = hv[i].y + g * ((xv[4 * i + 1] - mu) * rstd * wv4.y + bv4.y - hv[i].y);
    ov.z = hv[i].z + g * ((xv[4 * i + 2] - mu) * rstd * wv4.z + bv4.z - hv[i].z);
    ov.w = hv[i].w + g * ((xv[4 * i + 3] - mu) * rstd * wv4.w + bv4.w - hv[i].w);
    ((float4*)o)[t + 256 * i] = ov;
  }
}

// ---------------------------------------------------------------- launcher
extern "C" void kernel_launch(void* const* d_in, const int* in_sizes, int n_in,
                              void* d_out, int out_size, void* d_ws, size_t ws_size,
                              hipStream_t stream) {
  const float* hidden = (const float*)d_in[0];
  const float* mem    = (const float*)d_in[1];
  const unsigned char* mask = (const unsigned char*)d_in[2];
  const float* Wq = (const float*)d_in[3];
  const float* bq = (const float*)d_in[4];
  const float* Wk = (const float*)d_in[5];
  const float* bk = (const float*)d_in[6];
  const float* Wv = (const float*)d_in[7];
  const float* bv = (const float*)d_in[8];
  const float* Wo = (const float*)d_in[9];
  const float* bo = (const float*)d_in[10];
  const float* lnw1 = (const float*)d_in[11];
  const float* lnb1 = (const float*)d_in[12];
  const float* lnw2 = (const float*)d_in[13];
  const float* lnb2 = (const float*)d_in[14];
  const float* gate = (const float*)d_in[15];
  float* out = (float*)d_out;

  // workspace layout (f16 elements); hnorm is reused as ctx_h (disjoint lifetimes)
  _Float16* p = (_Float16*)d_ws;
  _Float16* hnorm = p; p += (size_t)8192 * 4096;      // 67.1 MB (later: ctx_h)
  _Float16* Qh    = p; p += (size_t)8192 * 512;       // 8.4 MB
  _Float16* memh  = p; p += (size_t)6000 * 1024;      // 12.3 MB
  _Float16* WqT   = p; p += (size_t)512 * 4096;       // [A][H]
  _Float16* WkT   = p; p += (size_t)512 * 1024;       // [A][D]
  _Float16* WvT   = p; p += (size_t)512 * 1024;
  _Float16* WoT   = p; p += (size_t)4096 * 512;       // [H][A]
  _Float16* Kp    = p; p += (size_t)B_ * TMP_ * A_;   // [B][1536][512]
  _Float16* VT    = p; p += (size_t)B_ * A_ * TMP_;   // [B][512][1536]
  _Float16* sc    = p; p += (size_t)B_ * LQ_ * TMP_;  // [B][2048][1536] scores->attn
  _Float16* ctx   = p; p += (size_t)8192 * 512;       // [8192][512]

  // 1. LN(hidden) -> hnorm (f16)
  ln1_kernel<<<8192, 256, 0, stream>>>(hidden, lnw1, lnb1, hnorm);
  // 2. mem -> f16
  cvt_h_kernel<<<2048, 256, 0, stream>>>((const float4*)mem, (half4v*)memh, 6000 * 1024 / 4);
  // 3. weight transposes -> [N][K] f16
  transpose_h_kernel<<<dim3(512 / 32, 4096 / 32), dim3(32, 8), 0, stream>>>(Wq, WqT, 4096, 512);
  transpose_h_kernel<<<dim3(512 / 32, 1024 / 32), dim3(32, 8), 0, stream>>>(Wk, WkT, 1024, 512);
  transpose_h_kernel<<<dim3(512 / 32, 1024 / 32), dim3(32, 8), 0, stream>>>(Wv, WvT, 1024, 512);
  transpose_h_kernel<<<dim3(4096 / 32, 512 / 32), dim3(32, 8), 0, stream>>>(Wo, WoT, 512, 4096);
  // 4. Q = hnorm @ Wq + bq          [8192][512]
  gemm_nt_kernel<0><<<dim3(4, 64, 1), 256, 0, stream>>>(hnorm, 0, WqT, 0, bq, Qh, 0,
                                                        8192, 4096, 512, 1.f);
  // 5. K = mem @ Wk + bk  -> Kp     [B][1536][512] (pad rows = dup of row 1499, masked later)
  gemm_nt_kernel<0><<<dim3(4, 12, 4), 256, 0, stream>>>(memh, (size_t)1500 * 1024, WkT, 0, bk,
                                                        Kp, (size_t)TMP_ * A_, 1500, 1024, 512, 1.f);
  // 6. V = mem @ Wv + bv -> VT (transposed out) [B][512][1536]
  gemm_nt_kernel<1><<<dim3(4, 12, 4), 256, 0, stream>>>(memh, (size_t)1500 * 1024, WvT, 0, bv,
                                                        VT, (size_t)A_ * TMP_, 1500, 1024, TMP_, 1.f);
  // 7. scores = Q @ K^T * 1/sqrt(A)  [B][2048][1536]
  gemm_nt_kernel<0><<<dim3(12, 16, 4), 256, 0, stream>>>(Qh, (size_t)LQ_ * A_, Kp, (size_t)TMP_ * A_,
                                                         nullptr, sc, (size_t)LQ_ * TMP_,
                                                         2048, 512, TMP_, 0.044194173824159216f);
  // 8. softmax (mask + pad) in-place -> attn (f16)
  softmax_kernel<<<8192, 256, 0, stream>>>(sc, mask);
  // 9. ctx = attn @ V    [8192][512]
  gemm_nt_kernel<0><<<dim3(4, 16, 4), 256, 0, stream>>>(sc, (size_t)LQ_ * TMP_, VT, (size_t)A_ * TMP_,
                                                        nullptr, ctx, (size_t)LQ_ * A_,
                                                        2048, TMP_, 512, 1.f);
  // 10. ctx_h = ctx @ Wo + bo -> reuse hnorm buffer  [8192][4096]
  gemm_nt_kernel<0><<<dim3(32, 64, 1), 256, 0, stream>>>(ctx, 0, WoT, 0, bo, hnorm, 0,
                                                         8192, 512, 4096, 1.f);
  // 11. out = hidden + g*(LN(hidden+ctx_h) - hidden)
  ln2_gate_kernel<<<8192, 256, 0, stream>>>(hidden, hnorm, lnw2, lnb2, gate, out);
}

// Round 2
// 568.934 us; speedup vs baseline: 1.1078x; 1.1078x over previous
//
#include <hip/hip_runtime.h>
#include <cstdint>
#include <cstddef>

// Problem constants
#define H_   4096
#define D_   1024
#define A_   512
#define B_   4
#define LQ_  2048
#define TM_  1500
#define TMP_ 1536   // TM padded to multiple of 128
#define EPS_ 1e-5f

typedef __attribute__((ext_vector_type(8))) _Float16 half8;
typedef __attribute__((ext_vector_type(4))) _Float16 half4v;
typedef __attribute__((ext_vector_type(4))) float f32x4;

// ---------------------------------------------------------------- helpers
__device__ __forceinline__ void gload_lds16(void* g, void* l) {
  // async global->LDS, 16B per lane; LDS dest = wave-uniform base + lane*16
  __builtin_amdgcn_global_load_lds((__attribute__((address_space(1))) void*)g,
                                   (__attribute__((address_space(3))) void*)l,
                                   16, 0, 0);
}

// ---------------------------------------------------------------- core 128x128 MFMA tile
// C[m][n] = scale * sum_k A[m][k] * Bt[n][k] (+ bias[n] for f16 modes)
// OUTMODE: 0 = f16 row-major, 1 = f16 transposed (C[n][m]), 2 = fp32 row-major (no bias)
// LDS chunk swizzle: global 16B chunk (cs ^ ((r>>1)&3)) lands in LDS slot cs ->
// reader slot j^((rsub>>1)&3); bank groups distinct over 8 consecutive rows (2-way = free).
template <int OUTMODE>
__device__ __forceinline__ void gemm_tile(
    const _Float16* __restrict__ A, int lda,
    const _Float16* __restrict__ Bt, int ldb,
    const float* __restrict__ bias,
    void* __restrict__ C, int ldc,
    int Mvalid, int m0, int n0, int kbase, int kiters, float scale,
    _Float16* As, _Float16* Bs) {
  const int tid = threadIdx.x;
  const int lane = tid & 63;
  const int wave = tid >> 6;

  f32x4 acc[4][4];
#pragma unroll
  for (int i = 0; i < 4; ++i)
#pragma unroll
    for (int j = 0; j < 4; ++j) acc[i][j] = (f32x4){0.f, 0.f, 0.f, 0.f};

  // staging: 128x32 f16 tile = 512 chunks of 16B; 256 threads x 2 chunks each
  const _Float16* gA[2];
  const _Float16* gB[2];
  _Float16* lA[2];
  _Float16* lB[2];
#pragma unroll
  for (int i = 0; i < 2; ++i) {
    const int c = wave * 64 + lane + 256 * i;
    const int r = c >> 2;
    const int cs = c & 3;
    const int col = (cs ^ ((r >> 1) & 3)) * 8;  // XOR-swizzled 16B chunk
    int ra = m0 + r;
    if (ra >= Mvalid) ra = Mvalid - 1;  // clamp (pad rows dup last valid row)
    gA[i] = A + (size_t)ra * lda + kbase + col;
    gB[i] = Bt + (size_t)(n0 + r) * ldb + kbase + col;
    lA[i] = As + wave * 512 + i * 2048;  // wave-uniform LDS base (linear layout)
    lB[i] = Bs + wave * 512 + i * 2048;
  }

  const int wm = (wave >> 1) * 64;
  const int wn = (wave & 1) * 64;
  const int rsub = lane & 15;
  const int j = lane >> 4;                 // which 16B chunk of the 32-wide K row
  const int slot = j ^ ((rsub >> 1) & 3);  // swizzled LDS slot (constant per lane)

  for (int kt = 0; kt < kiters; ++kt) {
    const int ko = kt * 32;
#pragma unroll
    for (int i = 0; i < 2; ++i) {
      gload_lds16((void*)(gA[i] + ko), (void*)lA[i]);
      gload_lds16((void*)(gB[i] + ko), (void*)lB[i]);
    }
    __syncthreads();
    half8 af[4], bfr[4];
#pragma unroll
    for (int x = 0; x < 4; ++x) {
      af[x]  = *(const half8*)&As[(wm + x * 16 + rsub) * 32 + slot * 8];
      bfr[x] = *(const half8*)&Bs[(wn + x * 16 + rsub) * 32 + slot * 8];
    }
#pragma unroll
    for (int mi = 0; mi < 4; ++mi)
#pragma unroll
      for (int ni = 0; ni < 4; ++ni)
        acc[mi][ni] = __builtin_amdgcn_mfma_f32_16x16x32_f16(af[mi], bfr[ni], acc[mi][ni], 0, 0, 0);
    __syncthreads();
  }

  const int cn = n0 + wn + rsub;
  const int rm = m0 + wm + j * 4;
#pragma unroll
  for (int ni = 0; ni < 4; ++ni) {
    const int n = cn + ni * 16;
    const float bi = (OUTMODE != 2 && bias) ? bias[n] : 0.f;
#pragma unroll
    for (int mi = 0; mi < 4; ++mi) {
#pragma unroll
      for (int r = 0; r < 4; ++r) {
        const int m = rm + mi * 16 + r;
        const float v = acc[mi][ni][r] * scale + bi;
        if (OUTMODE == 0) ((_Float16*)C)[(size_t)m * ldc + n] = (_Float16)v;
        else if (OUTMODE == 1) ((_Float16*)C)[(size_t)n * ldc + m] = (_Float16)v;
        else ((float*)C)[(size_t)m * ldc + n] = v;
      }
    }
  }
}

// ---------------------------------------------------------------- generic batched/split-K GEMM
template <int OUTMODE>
__global__ __launch_bounds__(256) void gemm_nt_kernel(
    const _Float16* __restrict__ Aall, size_t strideA, int lda,
    const _Float16* __restrict__ Btall, size_t strideB, int ldb,
    const float* __restrict__ bias,
    void* __restrict__ Call, size_t strideC, size_t strideS,
    int ldc, int Mvalid, int kiters, int nslices, int sliceK, float scale) {
  __shared__ __align__(16) _Float16 As[4096];
  __shared__ __align__(16) _Float16 Bs[4096];
  const int z = blockIdx.z;
  const int batch = z / nslices;
  const int slice = z % nslices;
  const _Float16* A = Aall + (size_t)batch * strideA;
  const _Float16* Bt = Btall + (size_t)batch * strideB;
  char* C = (char*)Call + ((size_t)batch * strideC + (size_t)slice * strideS) *
                          (OUTMODE == 2 ? 4 : 2);
  gemm_tile<OUTMODE>(A, lda, Bt, ldb, bias, (void*)C, ldc, Mvalid,
                     blockIdx.y * 128, blockIdx.x * 128, slice * sliceK, kiters,
                     scale, As, Bs);
}

// ---------------------------------------------------------------- fused Q + K + V projections
// blocks 0..511: Q split-K (ks=bid>>8), 512..703: K, 704..895: V(transposed out)
__global__ __launch_bounds__(256) void qkv_kernel(
    const _Float16* __restrict__ hnorm, const _Float16* __restrict__ WqT,
    float* __restrict__ Qpart,
    const _Float16* __restrict__ memh, const _Float16* __restrict__ WkT,
    const float* __restrict__ bk, _Float16* __restrict__ Kp,
    const _Float16* __restrict__ WvT, const float* __restrict__ bv,
    _Float16* __restrict__ VT) {
  __shared__ __align__(16) _Float16 As[4096];
  __shared__ __align__(16) _Float16 Bs[4096];
  const int bid = blockIdx.x;
  if (bid < 512) {
    const int nb = bid & 3, mb = (bid >> 2) & 63, ks = bid >> 8;
    gemm_tile<2>(hnorm, H_, WqT, H_, nullptr,
                 (void*)(Qpart + (size_t)ks * 8192 * A_), A_,
                 8192, mb * 128, nb * 128, ks * 2048, 64, 1.f, As, Bs);
  } else if (bid < 704) {
    const int t = bid - 512;
    const int nb = t & 3, mb = (t >> 2) % 12, b = t / 48;
    gemm_tile<0>(memh + (size_t)b * TM_ * D_, D_, WkT, D_, bk,
                 (void*)(Kp + (size_t)b * TMP_ * A_), A_,
                 TM_, mb * 128, nb * 128, 0, 32, 1.f, As, Bs);
  } else {
    const int t = bid - 704;
    const int nb = t & 3, mb = (t >> 2) % 12, b = t / 48;
    gemm_tile<1>(memh + (size_t)b * TM_ * D_, D_, WvT, D_, bv,
                 (void*)(VT + (size_t)b * A_ * TMP_), TMP_,
                 TM_, mb * 128, nb * 128, 0, 32, 1.f, As, Bs);
  }
}

// ---------------------------------------------------------------- split-K reduces
__global__ __launch_bounds__(256) void qreduce_kernel(
    const float* __restrict__ p, const float* __restrict__ bias,
    _Float16* __restrict__ out) {
  const size_t i = ((size_t)blockIdx.x * 256 + threadIdx.x) * 4;  // 8192*512 total
  const float4 a = *(const float4*)(p + i);
  const float4 b = *(const float4*)(p + (size_t)8192 * A_ + i);
  const float4 bi = *(const float4*)(bias + (i & (A_ - 1)));
  half4v o;
  o.x = (_Float16)(a.x + b.x + bi.x);
  o.y = (_Float16)(a.y + b.y + bi.y);
  o.z = (_Float16)(a.z + b.z + bi.z);
  o.w = (_Float16)(a.w + b.w + bi.w);
  *(half4v*)(out + i) = o;
}

__global__ __launch_bounds__(256) void areduce_kernel(
    const float* __restrict__ p, _Float16* __restrict__ out) {
  const size_t S = (size_t)B_ * LQ_ * A_;
  const size_t i = ((size_t)blockIdx.x * 256 + threadIdx.x) * 4;
  const float4 a = *(const float4*)(p + i);
  const float4 b = *(const float4*)(p + S + i);
  const float4 c = *(const float4*)(p + 2 * S + i);
  half4v o;
  o.x = (_Float16)(a.x + b.x + c.x);
  o.y = (_Float16)(a.y + b.y + c.y);
  o.z = (_Float16)(a.z + b.z + c.z);
  o.w = (_Float16)(a.w + b.w + c.w);
  *(half4v*)(out + i) = o;
}

// ---------------------------------------------------------------- LN1: h_norm = LN(hidden) -> f16
__global__ __launch_bounds__(256) void ln1_kernel(
    const float* __restrict__ hidden_, const float* __restrict__ w,
    const float* __restrict__ bvec, _Float16* __restrict__ y_) {
  const int row = blockIdx.x;
  const float* x = hidden_ + (size_t)row * H_;
  _Float16* y = y_ + (size_t)row * H_;
  const int t = threadIdx.x;
  float4 v[4];
  float s = 0.f, ss = 0.f;
#pragma unroll
  for (int i = 0; i < 4; ++i) {
    v[i] = ((const float4*)x)[t + 256 * i];
    s  += v[i].x + v[i].y + v[i].z + v[i].w;
    ss += v[i].x * v[i].x + v[i].y * v[i].y + v[i].z * v[i].z + v[i].w * v[i].w;
  }
  __shared__ float red[2][4];
  const int lane = t & 63, wv = t >> 6;
#pragma unroll
  for (int off = 32; off; off >>= 1) { s += __shfl_down(s, off); ss += __shfl_down(ss, off); }
  if (lane == 0) { red[0][wv] = s; red[1][wv] = ss; }
  __syncthreads();
  s  = red[0][0] + red[0][1] + red[0][2] + red[0][3];
  ss = red[1][0] + red[1][1] + red[1][2] + red[1][3];
  const float mu = s * (1.f / H_);
  const float var = ss * (1.f / H_) - mu * mu;
  const float rstd = rsqrtf(var + EPS_);
#pragma unroll
  for (int i = 0; i < 4; ++i) {
    float4 wv4 = ((const float4*)w)[t + 256 * i];
    float4 bv4 = ((const float4*)bvec)[t + 256 * i];
    half4v o;
    o.x = (_Float16)((v[i].x - mu) * rstd * wv4.x + bv4.x);
    o.y = (_Float16)((v[i].y - mu) * rstd * wv4.y + bv4.y);
    o.z = (_Float16)((v[i].z - mu) * rstd * wv4.z + bv4.z);
    o.w = (_Float16)((v[i].w - mu) * rstd * wv4.w + bv4.w);
    ((half4v*)y)[t + 256 * i] = o;
  }
}

// ---------------------------------------------------------------- fp32 -> f16 convert (mem)
__global__ __launch_bounds__(256) void cvt_h_kernel(
    const float4* __restrict__ in, half4v* __restrict__ out, int n4) {
  for (int i = blockIdx.x * 256 + threadIdx.x; i < n4; i += gridDim.x * 256) {
    float4 f = in[i];
    half4v o;
    o.x = (_Float16)f.x; o.y = (_Float16)f.y; o.z = (_Float16)f.z; o.w = (_Float16)f.w;
    out[i] = o;
  }
}

// ---------------------------------------------------------------- transpose fp32 [R][C] -> f16 [C][R]
__global__ __launch_bounds__(256) void transpose_h_kernel(
    const float* __restrict__ in, _Float16* __restrict__ out, int R, int C) {
  __shared__ float tile[32][33];
  const int tx = threadIdx.x, ty = threadIdx.y;
  const int c0 = blockIdx.x * 32, r0 = blockIdx.y * 32;
#pragma unroll
  for (int i = 0; i < 32; i += 8)
    tile[ty + i][tx] = in[(size_t)(r0 + ty + i) * C + (c0 + tx)];
  __syncthreads();
#pragma unroll
  for (int i = 0; i < 32; i += 8)
    out[(size_t)(c0 + ty + i) * R + (r0 + tx)] = (_Float16)tile[tx][ty + i];
}

// ---------------------------------------------------------------- softmax rows (in-place f16)
__global__ __launch_bounds__(256) void softmax_kernel(
    _Float16* __restrict__ scores, const unsigned char* __restrict__ mask) {
  const int row = blockIdx.x;          // B*LQ rows
  const int b = row >> 11;             // / LQ_
  _Float16* s = scores + (size_t)row * TMP_;
  const unsigned char* mk = mask + (size_t)b * TM_;
  const int t = threadIdx.x;
  float v[6];
#pragma unroll
  for (int i = 0; i < 6; ++i) {
    const int c = t + 256 * i;
    float x;
    if (c >= TM_) x = -INFINITY;                 // pad -> exactly zero weight
    else if (mk[c]) x = -1e30f;                  // reference mask semantics
    else x = (float)s[c];
    v[i] = x;
  }
  __shared__ float red[4];
  const int lane = t & 63, wv = t >> 6;
  float m = v[0];
#pragma unroll
  for (int i = 1; i < 6; ++i) m = fmaxf(m, v[i]);
#pragma unroll
  for (int off = 32; off; off >>= 1) m = fmaxf(m, __shfl_down(m, off));
  if (lane == 0) red[wv] = m;
  __syncthreads();
  m = fmaxf(fmaxf(red[0], red[1]), fmaxf(red[2], red[3]));
  float sum = 0.f;
#pragma unroll
  for (int i = 0; i < 6; ++i) { v[i] = __expf(v[i] - m); sum += v[i]; }
  __syncthreads();
#pragma unroll
  for (int off = 32; off; off >>= 1) sum += __shfl_down(sum, off);
  if (lane == 0) red[wv] = sum;
  __syncthreads();
  sum = red[0] + red[1] + red[2] + red[3];
  const float inv = 1.f / sum;
#pragma unroll
  for (int i = 0; i < 6; ++i) s[t + 256 * i] = (_Float16)(v[i] * inv);
}

// ---------------------------------------------------------------- LN2 + gate epilogue -> out (fp32)
__global__ __launch_bounds__(256) void ln2_gate_kernel(
    const float* __restrict__ hidden_, const _Float16* __restrict__ ctxh_,
    const float* __restrict__ w, const float* __restrict__ bvec,
    const float* __restrict__ gate_logit, float* __restrict__ out_) {
  const int row = blockIdx.x;
  const float* h = hidden_ + (size_t)row * H_;
  const _Float16* c = ctxh_ + (size_t)row * H_;
  float* o = out_ + (size_t)row * H_;
  const int t = threadIdx.x;
  float4 hv[4];
  float xv[16];
  float s = 0.f, ss = 0.f;
#pragma unroll
  for (int i = 0; i < 4; ++i) {
    hv[i] = ((const float4*)h)[t + 256 * i];
    half4v cv = ((const half4v*)c)[t + 256 * i];
    xv[4 * i + 0] = hv[i].x + (float)cv.x;
    xv[4 * i + 1] = hv[i].y + (float)cv.y;
    xv[4 * i + 2] = hv[i].z + (float)cv.z;
    xv[4 * i + 3] = hv[i].w + (float)cv.w;
    s  += xv[4 * i + 0] + xv[4 * i + 1] + xv[4 * i + 2] + xv[4 * i + 3];
    ss += xv[4 * i + 0] * xv[4 * i + 0] + xv[4 * i + 1] * xv[4 * i + 1] +
          xv[4 * i + 2] * xv[4 * i + 2] + xv[4 * i + 3] * xv[4 * i + 3];
  }
  __shared__ float red[2][4];
  const int lane = t & 63, wv = t >> 6;
#pragma unroll
  for (int off = 32; off; off >>= 1) { s += __shfl_down(s, off); ss += __shfl_down(ss, off); }
  if (lane == 0) { red[0][wv] = s; red[1][wv] = ss; }
  __syncthreads();
  s  = red[0][0] + red[0][1] + red[0][2] + red[0][3];
  ss = red[1][0] + red[1][1] + red[1][2] + red[1][3];
  const float mu = s * (1.f / H_);
  const float var = ss * (1.f / H_) - mu * mu;
  const float rstd = rsqrtf(var + EPS_);
  const float g = 1.f / (1.f + __expf(-gate_logit[0]));
#pragma unroll
  for (int i = 0; i < 4; ++i) {
    float4 wv4 = ((const float4*)w)[t + 256 * i];
    float4 bv4 = ((const float4*)bvec)[t + 256 * i];
    float4 ov;
    ov.x = hv[i].x + g * ((xv[4 * i + 0] - mu) * rstd * wv4.x + bv4.x - hv[i].x);
    ov.y = hv[i].y + g * ((xv[4 * i + 1] - mu) * rstd * wv4.y + bv4.y - hv[i].y);
    ov.z = hv[i].z + g * ((xv[4 * i + 2] - mu) * rstd * wv4.z + bv4.z - hv[i].z);
    ov.w = hv[i].w + g * ((xv[4 * i + 3] - mu) * rstd * wv4.w + bv4.w - hv[i].w);
    ((float4*)o)[t + 256 * i] = ov;
  }
}

// ---------------------------------------------------------------- launcher
extern "C" void kernel_launch(void* const* d_in, const int* in_sizes, int n_in,
                              void* d_out, int out_size, void* d_ws, size_t ws_size,
                              hipStream_t stream) {
  const float* hidden = (const float*)d_in[0];
  const float* mem    = (const float*)d_in[1];
  const unsigned char* mask = (const unsigned char*)d_in[2];
  const float* Wq = (const float*)d_in[3];
  const float* bq = (const float*)d_in[4];
  const float* Wk = (const float*)d_in[5];
  const float* bk = (const float*)d_in[6];
  const float* Wv = (const float*)d_in[7];
  const float* bv = (const float*)d_in[8];
  const float* Wo = (const float*)d_in[9];
  const float* bo = (const float*)d_in[10];
  const float* lnw1 = (const float*)d_in[11];
  const float* lnb1 = (const float*)d_in[12];
  const float* lnw2 = (const float*)d_in[13];
  const float* lnb2 = (const float*)d_in[14];
  const float* gate = (const float*)d_in[15];
  float* out = (float*)d_out;

  // workspace layout (f16 elements)
  _Float16* p = (_Float16*)d_ws;
  _Float16* hnorm = p; p += (size_t)8192 * H_;        // 67.1 MB; later: attn fp32 partials (50.3 MB), then ctx_h
  _Float16* Qh    = p; p += (size_t)8192 * A_;        // 8.4 MB
  _Float16* memh  = p; p += (size_t)6000 * D_;        // 12.3 MB
  _Float16* WqT   = p; p += (size_t)A_ * H_;          // [A][H]
  _Float16* WkT   = p; p += (size_t)A_ * D_;          // [A][D]
  _Float16* WvT   = p; p += (size_t)A_ * D_;
  _Float16* WoT   = p; p += (size_t)H_ * A_;          // [H][A]
  _Float16* Kp    = p; p += (size_t)B_ * TMP_ * A_;   // [B][1536][512]
  _Float16* VT    = p; p += (size_t)B_ * A_ * TMP_;   // [B][512][1536]
  _Float16* sc    = p; p += (size_t)B_ * LQ_ * TMP_;  // [B][2048][1536] scores->attn
  _Float16* ctx   = p; p += (size_t)8192 * A_;        // [8192][512]
  // aliases (disjoint lifetimes):
  float* Qpart = (float*)sc;      // 2 x 8192 x 512 fp32 = 33.55 MB == sizeof(sc)+sizeof(ctx)
  float* Apart = (float*)hnorm;   // 3 x 4 x 2048 x 512 fp32 = 50.3 MB <= 67.1 MB

  // 1. elementwise prep
  ln1_kernel<<<8192, 256, 0, stream>>>(hidden, lnw1, lnb1, hnorm);
  cvt_h_kernel<<<2048, 256, 0, stream>>>((const float4*)mem, (half4v*)memh, 6000 * D_ / 4);
  transpose_h_kernel<<<dim3(A_ / 32, H_ / 32), dim3(32, 8), 0, stream>>>(Wq, WqT, H_, A_);
  transpose_h_kernel<<<dim3(A_ / 32, D_ / 32), dim3(32, 8), 0, stream>>>(Wk, WkT, D_, A_);
  transpose_h_kernel<<<dim3(A_ / 32, D_ / 32), dim3(32, 8), 0, stream>>>(Wv, WvT, D_, A_);
  transpose_h_kernel<<<dim3(H_ / 32, A_ / 32), dim3(32, 8), 0, stream>>>(Wo, WoT, A_, H_);
  // 2. fused Q(split-K x2) + K + V projections: 896 blocks (~3.5/CU)
  qkv_kernel<<<896, 256, 0, stream>>>(hnorm, WqT, Qpart, memh, WkT, bk, Kp, WvT, bv, VT);
  // 3. Q = sum partials + bq -> f16
  qreduce_kernel<<<4096, 256, 0, stream>>>(Qpart, bq, Qh);
  // 4. scores = Q @ K^T * 1/sqrt(A)  [B][2048][1536]
  gemm_nt_kernel<0><<<dim3(12, 16, 4), 256, 0, stream>>>(
      Qh, (size_t)LQ_ * A_, A_, Kp, (size_t)TMP_ * A_, A_, nullptr,
      (void*)sc, (size_t)LQ_ * TMP_, 0, TMP_, LQ_, 16, 1, 0, 0.044194173824159216f);
  // 5. softmax (mask + pad) in-place -> attn (f16)
  softmax_kernel<<<8192, 256, 0, stream>>>(sc, mask);
  // 6. ctx partials = attn @ V, split-K x3 (K=512 each): 768 blocks
  gemm_nt_kernel<2><<<dim3(4, 16, 12), 256, 0, stream>>>(
      sc, (size_t)LQ_ * TMP_, TMP_, VT, (size_t)A_ * TMP_, TMP_, nullptr,
      (void*)Apart, (size_t)LQ_ * A_, (size_t)B_ * LQ_ * A_, A_, LQ_, 16, 3, 512, 1.f);
  // 7. ctx = sum partials -> f16
  areduce_kernel<<<4096, 256, 0, stream>>>(Apart, ctx);
  // 8. ctx_h = ctx @ Wo + bo -> reuse hnorm buffer  [8192][4096] (2048 blocks)
  gemm_nt_kernel<0><<<dim3(32, 64, 1), 256, 0, stream>>>(
      ctx, 0, A_, WoT, 0, A_, bo, (void*)hnorm, 0, 0, H_, 8192, 16, 1, 0, 1.f);
  // 9. out = hidden + g*(LN(hidden+ctx_h) - hidden)
  ln2_gate_kernel<<<8192, 256, 0, stream>>>(hidden, hnorm, lnw2, lnb2, gate, out);
}

// Round 3
// 523.801 us; speedup vs baseline: 1.2032x; 1.0862x over previous
//
#include <hip/hip_runtime.h>
#include <cstdint>
#include <cstddef>

// Problem constants
#define H_   4096
#define D_   1024
#define A_   512
#define B_   4
#define LQ_  2048
#define TM_  1500
#define TMP_ 1536   // TM padded to multiple of 128
#define EPS_ 1e-5f

typedef __attribute__((ext_vector_type(8))) _Float16 half8;
typedef __attribute__((ext_vector_type(4))) _Float16 half4v;
typedef __attribute__((ext_vector_type(4))) float f32x4;

// ---------------------------------------------------------------- helpers
__device__ __forceinline__ void gload_lds16(void* g, void* l) {
  // async global->LDS, 16B per lane; LDS dest = wave-uniform base + lane*16
  __builtin_amdgcn_global_load_lds((__attribute__((address_space(1))) void*)g,
                                   (__attribute__((address_space(3))) void*)l,
                                   16, 0, 0);
}

// ---------------------------------------------------------------- core 128x128 MFMA tile
// C[m][n] = scale * sum_k A[m][k] * Bt[n][k] (+ bias[n])
// OUTMODE: 0 = f16 row-major, 1 = f16 transposed (C[n][m], packed 8B stores),
//          2 = fp32 row-major (no bias), 3 = exp-scores: write f16 exp(v*scale)
//              with mask/pad zeroing + per-row atomic sums into lsum.
// LDS chunk swizzle: global 16B chunk (cs ^ ((r>>1)&3)) lands in LDS slot cs ->
// reader slot j^((rsub>>1)&3); 0 bank conflicts measured (R2).
template <int OUTMODE>
__device__ __forceinline__ void gemm_tile(
    const _Float16* __restrict__ A, int lda,
    const _Float16* __restrict__ Bt, int ldb,
    const float* __restrict__ bias,
    void* __restrict__ C, int ldc,
    int Mvalid, int m0, int n0, int kbase, int kiters, float scale,
    _Float16* As, _Float16* Bs,
    const unsigned char* __restrict__ mrow, float* __restrict__ lsum, int nvalid) {
  const int tid = threadIdx.x;
  const int lane = tid & 63;
  const int wave = tid >> 6;

  f32x4 acc[4][4];
#pragma unroll
  for (int i = 0; i < 4; ++i)
#pragma unroll
    for (int jj = 0; jj < 4; ++jj) acc[i][jj] = (f32x4){0.f, 0.f, 0.f, 0.f};

  // staging: 128x32 f16 tile = 512 chunks of 16B; 256 threads x 2 chunks each
  const _Float16* gA[2];
  const _Float16* gB[2];
  _Float16* lA[2];
  _Float16* lB[2];
#pragma unroll
  for (int i = 0; i < 2; ++i) {
    const int c = wave * 64 + lane + 256 * i;
    const int r = c >> 2;
    const int cs = c & 3;
    const int col = (cs ^ ((r >> 1) & 3)) * 8;  // XOR-swizzled 16B chunk
    int ra = m0 + r;
    if (ra >= Mvalid) ra = Mvalid - 1;  // clamp (pad rows dup last valid row)
    gA[i] = A + (size_t)ra * lda + kbase + col;
    gB[i] = Bt + (size_t)(n0 + r) * ldb + kbase + col;
    lA[i] = As + wave * 512 + i * 2048;  // wave-uniform LDS base (linear layout)
    lB[i] = Bs + wave * 512 + i * 2048;
  }

  const int wm = (wave >> 1) * 64;
  const int wn = (wave & 1) * 64;
  const int rsub = lane & 15;
  const int j = lane >> 4;                 // which 16B chunk of the 32-wide K row
  const int slot = j ^ ((rsub >> 1) & 3);  // swizzled LDS slot (constant per lane)

  for (int kt = 0; kt < kiters; ++kt) {
    const int ko = kt * 32;
#pragma unroll
    for (int i = 0; i < 2; ++i) {
      gload_lds16((void*)(gA[i] + ko), (void*)lA[i]);
      gload_lds16((void*)(gB[i] + ko), (void*)lB[i]);
    }
    __syncthreads();
    half8 af[4], bfr[4];
#pragma unroll
    for (int x = 0; x < 4; ++x) {
      af[x]  = *(const half8*)&As[(wm + x * 16 + rsub) * 32 + slot * 8];
      bfr[x] = *(const half8*)&Bs[(wn + x * 16 + rsub) * 32 + slot * 8];
    }
#pragma unroll
    for (int mi = 0; mi < 4; ++mi)
#pragma unroll
      for (int ni = 0; ni < 4; ++ni)
        acc[mi][ni] = __builtin_amdgcn_mfma_f32_16x16x32_f16(af[mi], bfr[ni], acc[mi][ni], 0, 0, 0);
    __syncthreads();
  }

  const int cn = n0 + wn + rsub;
  const int rm = m0 + wm + j * 4;

  if (OUTMODE == 3) {
    bool ok[4];
#pragma unroll
    for (int ni = 0; ni < 4; ++ni) {
      const int n = cn + ni * 16;
      const int nc = n < nvalid ? n : nvalid - 1;   // clamped (always in-bounds) load
      ok[ni] = (n < nvalid) && (mrow[nc] == 0);
    }
#pragma unroll
    for (int mi = 0; mi < 4; ++mi) {
#pragma unroll
      for (int r = 0; r < 4; ++r) {
        const int m = rm + mi * 16 + r;
        float rowsum = 0.f;
#pragma unroll
        for (int ni = 0; ni < 4; ++ni) {
          const int n = cn + ni * 16;
          const float e = ok[ni] ? __expf(acc[mi][ni][r] * scale) : 0.f;
          ((_Float16*)C)[(size_t)m * ldc + n] = (_Float16)e;
          rowsum += e;
        }
        // reduce over the 16-lane n-group, one atomic per row per group
#pragma unroll
        for (int d = 1; d < 16; d <<= 1) rowsum += __shfl_xor(rowsum, d);
        if (rsub == 0) atomicAdd(&lsum[m], rowsum);
      }
    }
    return;
  }

  if (OUTMODE == 1) {
    // C[n][m]: 4 consecutive m per lane -> packed 8B stores
#pragma unroll
    for (int ni = 0; ni < 4; ++ni) {
      const int n = cn + ni * 16;
      const float bi = bias ? bias[n] : 0.f;
#pragma unroll
      for (int mi = 0; mi < 4; ++mi) {
        half4v pk;
#pragma unroll
        for (int r = 0; r < 4; ++r) pk[r] = (_Float16)(acc[mi][ni][r] * scale + bi);
        *(half4v*)&((_Float16*)C)[(size_t)n * ldc + rm + mi * 16] = pk;
      }
    }
    return;
  }

#pragma unroll
  for (int ni = 0; ni < 4; ++ni) {
    const int n = cn + ni * 16;
    const float bi = (OUTMODE == 0 && bias) ? bias[n] : 0.f;
#pragma unroll
    for (int mi = 0; mi < 4; ++mi) {
#pragma unroll
      for (int r = 0; r < 4; ++r) {
        const int m = rm + mi * 16 + r;
        const float v = acc[mi][ni][r] * scale + bi;
        if (OUTMODE == 0) ((_Float16*)C)[(size_t)m * ldc + n] = (_Float16)v;
        else ((float*)C)[(size_t)m * ldc + n] = v;
      }
    }
  }
}

// ---------------------------------------------------------------- generic batched/split-K GEMM
template <int OUTMODE>
__global__ __launch_bounds__(256) void gemm_nt_kernel(
    const _Float16* __restrict__ Aall, size_t strideA, int lda,
    const _Float16* __restrict__ Btall, size_t strideB, int ldb,
    const float* __restrict__ bias,
    void* __restrict__ Call, size_t strideC, size_t strideS,
    int ldc, int Mvalid, int kiters, int nslices, int sliceK, float scale) {
  __shared__ __align__(16) _Float16 As[4096];
  __shared__ __align__(16) _Float16 Bs[4096];
  const int z = blockIdx.z;
  const int batch = z / nslices;
  const int slice = z % nslices;
  const _Float16* A = Aall + (size_t)batch * strideA;
  const _Float16* Bt = Btall + (size_t)batch * strideB;
  char* C = (char*)Call + ((size_t)batch * strideC + (size_t)slice * strideS) *
                          (OUTMODE == 2 ? 4 : 2);
  gemm_tile<OUTMODE>(A, lda, Bt, ldb, bias, (void*)C, ldc, Mvalid,
                     blockIdx.y * 128, blockIdx.x * 128, slice * sliceK, kiters,
                     scale, As, Bs, nullptr, nullptr, 0);
}

// ---------------------------------------------------------------- scores GEMM + fused exp/mask + row sums
__global__ __launch_bounds__(256) void scores_kernel(
    const _Float16* __restrict__ Qh, const _Float16* __restrict__ Kp,
    _Float16* __restrict__ sc, const unsigned char* __restrict__ mask,
    float* __restrict__ lsum) {
  __shared__ __align__(16) _Float16 As[4096];
  __shared__ __align__(16) _Float16 Bs[4096];
  const int b = blockIdx.z;
  gemm_tile<3>(Qh + (size_t)b * LQ_ * A_, A_, Kp + (size_t)b * TMP_ * A_, A_, nullptr,
               (void*)(sc + (size_t)b * LQ_ * TMP_), TMP_, LQ_,
               blockIdx.y * 128, blockIdx.x * 128, 0, 16, 0.044194173824159216f,
               As, Bs, mask + (size_t)b * TM_, lsum + (size_t)b * LQ_, TM_);
}

// ---------------------------------------------------------------- fused Q + K + V projections
// blocks 0..511: Q split-K (ks=bid>>8), 512..703: K, 704..895: V(transposed out)
__global__ __launch_bounds__(256) void qkv_kernel(
    const _Float16* __restrict__ hnorm, const _Float16* __restrict__ WqT,
    float* __restrict__ Qpart,
    const _Float16* __restrict__ memh, const _Float16* __restrict__ WkT,
    const float* __restrict__ bk, _Float16* __restrict__ Kp,
    const _Float16* __restrict__ WvT, const float* __restrict__ bv,
    _Float16* __restrict__ VT) {
  __shared__ __align__(16) _Float16 As[4096];
  __shared__ __align__(16) _Float16 Bs[4096];
  const int bid = blockIdx.x;
  if (bid < 512) {
    const int nb = bid & 3, mb = (bid >> 2) & 63, ks = bid >> 8;
    gemm_tile<2>(hnorm, H_, WqT, H_, nullptr,
                 (void*)(Qpart + (size_t)ks * 8192 * A_), A_,
                 8192, mb * 128, nb * 128, ks * 2048, 64, 1.f, As, Bs,
                 nullptr, nullptr, 0);
  } else if (bid < 704) {
    const int t = bid - 512;
    const int nb = t & 3, mb = (t >> 2) % 12, b = t / 48;
    gemm_tile<0>(memh + (size_t)b * TM_ * D_, D_, WkT, D_, bk,
                 (void*)(Kp + (size_t)b * TMP_ * A_), A_,
                 TM_, mb * 128, nb * 128, 0, 32, 1.f, As, Bs,
                 nullptr, nullptr, 0);
  } else {
    const int t = bid - 704;
    const int nb = t & 3, mb = (t >> 2) % 12, b = t / 48;
    gemm_tile<1>(memh + (size_t)b * TM_ * D_, D_, WvT, D_, bv,
                 (void*)(VT + (size_t)b * A_ * TMP_), TMP_,
                 TM_, mb * 128, nb * 128, 0, 32, 1.f, As, Bs,
                 nullptr, nullptr, 0);
  }
}

// ---------------------------------------------------------------- split-K reduces
// blocks >= 4096 zero the lsum buffer (8192 floats) for the scores pass
__global__ __launch_bounds__(256) void qreduce_kernel(
    const float* __restrict__ p, const float* __restrict__ bias,
    _Float16* __restrict__ out, float* __restrict__ lsum) {
  const int bid = blockIdx.x;
  if (bid >= 4096) {
    lsum[(bid - 4096) * 256 + threadIdx.x] = 0.f;
    return;
  }
  const size_t i = ((size_t)bid * 256 + threadIdx.x) * 4;  // 8192*512 total
  const float4 a = *(const float4*)(p + i);
  const float4 b = *(const float4*)(p + (size_t)8192 * A_ + i);
  const float4 bi = *(const float4*)(bias + (i & (A_ - 1)));
  half4v o;
  o.x = (_Float16)(a.x + b.x + bi.x);
  o.y = (_Float16)(a.y + b.y + bi.y);
  o.z = (_Float16)(a.z + b.z + bi.z);
  o.w = (_Float16)(a.w + b.w + bi.w);
  *(half4v*)(out + i) = o;
}

__global__ __launch_bounds__(256) void areduce_kernel(
    const float* __restrict__ p, const float* __restrict__ lsum,
    _Float16* __restrict__ out) {
  const size_t S = (size_t)B_ * LQ_ * A_;
  const size_t i = ((size_t)blockIdx.x * 256 + threadIdx.x) * 4;
  const float4 a = *(const float4*)(p + i);
  const float4 b = *(const float4*)(p + S + i);
  const float4 c = *(const float4*)(p + 2 * S + i);
  const float inv = 1.f / lsum[i >> 9];  // row = i / 512; all 4 elems same row
  half4v o;
  o.x = (_Float16)((a.x + b.x + c.x) * inv);
  o.y = (_Float16)((a.y + b.y + c.y) * inv);
  o.z = (_Float16)((a.z + b.z + c.z) * inv);
  o.w = (_Float16)((a.w + b.w + c.w) * inv);
  *(half4v*)(out + i) = o;
}

// ---------------------------------------------------------------- fused prep:
// blocks [0,8192): LN1 rows; [8192,9692): mem fp32->f16; rest: 4 weight transposes
__global__ __launch_bounds__(256) void prep_kernel(
    const float* __restrict__ hidden, const float* __restrict__ lnw,
    const float* __restrict__ lnb, _Float16* __restrict__ hnorm,
    const float* __restrict__ mem, _Float16* __restrict__ memh,
    const float* __restrict__ Wq, _Float16* __restrict__ WqT,
    const float* __restrict__ Wk, _Float16* __restrict__ WkT,
    const float* __restrict__ Wv, _Float16* __restrict__ WvT,
    const float* __restrict__ Wo, _Float16* __restrict__ WoT) {
  __shared__ float smem[32 * 33];
  int bid = blockIdx.x;
  const int t = threadIdx.x;
  if (bid < 8192) {  // ---- LN1 row
    const float* x = hidden + (size_t)bid * H_;
    _Float16* y = hnorm + (size_t)bid * H_;
    float4 v[4];
    float s = 0.f, ss = 0.f;
#pragma unroll
    for (int i = 0; i < 4; ++i) {
      v[i] = ((const float4*)x)[t + 256 * i];
      s  += v[i].x + v[i].y + v[i].z + v[i].w;
      ss += v[i].x * v[i].x + v[i].y * v[i].y + v[i].z * v[i].z + v[i].w * v[i].w;
    }
    const int lane = t & 63, wv = t >> 6;
#pragma unroll
    for (int off = 32; off; off >>= 1) { s += __shfl_down(s, off); ss += __shfl_down(ss, off); }
    if (lane == 0) { smem[wv] = s; smem[4 + wv] = ss; }
    __syncthreads();
    s  = smem[0] + smem[1] + smem[2] + smem[3];
    ss = smem[4] + smem[5] + smem[6] + smem[7];
    const float mu = s * (1.f / H_);
    const float var = ss * (1.f / H_) - mu * mu;
    const float rstd = rsqrtf(var + EPS_);
#pragma unroll
    for (int i = 0; i < 4; ++i) {
      float4 wv4 = ((const float4*)lnw)[t + 256 * i];
      float4 bv4 = ((const float4*)lnb)[t + 256 * i];
      half4v o;
      o.x = (_Float16)((v[i].x - mu) * rstd * wv4.x + bv4.x);
      o.y = (_Float16)((v[i].y - mu) * rstd * wv4.y + bv4.y);
      o.z = (_Float16)((v[i].z - mu) * rstd * wv4.z + bv4.z);
      o.w = (_Float16)((v[i].w - mu) * rstd * wv4.w + bv4.w);
      ((half4v*)y)[t + 256 * i] = o;
    }
    return;
  }
  bid -= 8192;
  if (bid < 1500) {  // ---- mem fp32 -> f16
    const size_t i = ((size_t)bid * 256 + t) * 4;
    float4 f = *(const float4*)(mem + i);
    half4v o;
    o.x = (_Float16)f.x; o.y = (_Float16)f.y; o.z = (_Float16)f.z; o.w = (_Float16)f.w;
    *(half4v*)(memh + i) = o;
    return;
  }
  bid -= 1500;
  // ---- weight transpose fp32 [R][C] -> f16 [C][R]
  const float* src;
  _Float16* dst;
  int R, C;
  if (bid < 2048) { src = Wq; dst = WqT; R = 4096; C = 512; }
  else if (bid < 2048 + 512) { bid -= 2048; src = Wk; dst = WkT; R = 1024; C = 512; }
  else if (bid < 2048 + 1024) { bid -= 2048 + 512; src = Wv; dst = WvT; R = 1024; C = 512; }
  else { bid -= 2048 + 1024; src = Wo; dst = WoT; R = 512; C = 4096; }
  const int nbx = C / 32;
  const int bx = bid % nbx, by = bid / nbx;
  const int tx = t & 31, ty = t >> 5;
  const int c0 = bx * 32, r0 = by * 32;
#pragma unroll
  for (int i = 0; i < 32; i += 8)
    smem[(ty + i) * 33 + tx] = src[(size_t)(r0 + ty + i) * C + c0 + tx];
  __syncthreads();
#pragma unroll
  for (int i = 0; i < 32; i += 8)
    dst[(size_t)(c0 + ty + i) * R + r0 + tx] = (_Float16)smem[tx * 33 + ty + i];
}

// ---------------------------------------------------------------- LN2 + gate epilogue -> out (fp32)
__global__ __launch_bounds__(256) void ln2_gate_kernel(
    const float* __restrict__ hidden_, const _Float16* __restrict__ ctxh_,
    const float* __restrict__ w, const float* __restrict__ bvec,
    const float* __restrict__ gate_logit, float* __restrict__ out_) {
  const int row = blockIdx.x;
  const float* h = hidden_ + (size_t)row * H_;
  const _Float16* c = ctxh_ + (size_t)row * H_;
  float* o = out_ + (size_t)row * H_;
  const int t = threadIdx.x;
  float4 hv[4];
  float xv[16];
  float s = 0.f, ss = 0.f;
#pragma unroll
  for (int i = 0; i < 4; ++i) {
    hv[i] = ((const float4*)h)[t + 256 * i];
    half4v cv = ((const half4v*)c)[t + 256 * i];
    xv[4 * i + 0] = hv[i].x + (float)cv.x;
    xv[4 * i + 1] = hv[i].y + (float)cv.y;
    xv[4 * i + 2] = hv[i].z + (float)cv.z;
    xv[4 * i + 3] = hv[i].w + (float)cv.w;
    s  += xv[4 * i + 0] + xv[4 * i + 1] + xv[4 * i + 2] + xv[4 * i + 3];
    ss += xv[4 * i + 0] * xv[4 * i + 0] + xv[4 * i + 1] * xv[4 * i + 1] +
          xv[4 * i + 2] * xv[4 * i + 2] + xv[4 * i + 3] * xv[4 * i + 3];
  }
  __shared__ float red[2][4];
  const int lane = t & 63, wv = t >> 6;
#pragma unroll
  for (int off = 32; off; off >>= 1) { s += __shfl_down(s, off); ss += __shfl_down(ss, off); }
  if (lane == 0) { red[0][wv] = s; red[1][wv] = ss; }
  __syncthreads();
  s  = red[0][0] + red[0][1] + red[0][2] + red[0][3];
  ss = red[1][0] + red[1][1] + red[1][2] + red[1][3];
  const float mu = s * (1.f / H_);
  const float var = ss * (1.f / H_) - mu * mu;
  const float rstd = rsqrtf(var + EPS_);
  const float g = 1.f / (1.f + __expf(-gate_logit[0]));
#pragma unroll
  for (int i = 0; i < 4; ++i) {
    float4 wv4 = ((const float4*)w)[t + 256 * i];
    float4 bv4 = ((const float4*)bvec)[t + 256 * i];
    float4 ov;
    ov.x = hv[i].x + g * ((xv[4 * i + 0] - mu) * rstd * wv4.x + bv4.x - hv[i].x);
    ov.y = hv[i].y + g * ((xv[4 * i + 1] - mu) * rstd * wv4.y + bv4.y - hv[i].y);
    ov.z = hv[i].z + g * ((xv[4 * i + 2] - mu) * rstd * wv4.z + bv4.z - hv[i].z);
    ov.w = hv[i].w + g * ((xv[4 * i + 3] - mu) * rstd * wv4.w + bv4.w - hv[i].w);
    ((float4*)o)[t + 256 * i] = ov;
  }
}

// ---------------------------------------------------------------- launcher
extern "C" void kernel_launch(void* const* d_in, const int* in_sizes, int n_in,
                              void* d_out, int out_size, void* d_ws, size_t ws_size,
                              hipStream_t stream) {
  const float* hidden = (const float*)d_in[0];
  const float* mem    = (const float*)d_in[1];
  const unsigned char* mask = (const unsigned char*)d_in[2];
  const float* Wq = (const float*)d_in[3];
  const float* bq = (const float*)d_in[4];
  const float* Wk = (const float*)d_in[5];
  const float* bk = (const float*)d_in[6];
  const float* Wv = (const float*)d_in[7];
  const float* bv = (const float*)d_in[8];
  const float* Wo = (const float*)d_in[9];
  const float* bo = (const float*)d_in[10];
  const float* lnw1 = (const float*)d_in[11];
  const float* lnb1 = (const float*)d_in[12];
  const float* lnw2 = (const float*)d_in[13];
  const float* lnb2 = (const float*)d_in[14];
  const float* gate = (const float*)d_in[15];
  float* out = (float*)d_out;

  // workspace layout (f16 elements)
  _Float16* p = (_Float16*)d_ws;
  _Float16* hnorm = p; p += (size_t)8192 * H_;        // 67.1 MB; later: attn fp32 partials (50.3 MB), then ctx_h
  _Float16* Qh    = p; p += (size_t)8192 * A_;        // 8.4 MB
  _Float16* memh  = p; p += (size_t)6000 * D_;        // 12.3 MB
  _Float16* WqT   = p; p += (size_t)A_ * H_;          // [A][H]
  _Float16* WkT   = p; p += (size_t)A_ * D_;          // [A][D] (dead after qkv -> lsum alias)
  _Float16* WvT   = p; p += (size_t)A_ * D_;
  _Float16* WoT   = p; p += (size_t)H_ * A_;          // [H][A]
  _Float16* Kp    = p; p += (size_t)B_ * TMP_ * A_;   // [B][1536][512]
  _Float16* VT    = p; p += (size_t)B_ * A_ * TMP_;   // [B][512][1536]
  _Float16* sc    = p; p += (size_t)B_ * LQ_ * TMP_;  // [B][2048][1536] exp-scores
  _Float16* ctx   = p; p += (size_t)8192 * A_;        // [8192][512]
  // aliases (disjoint lifetimes):
  float* Qpart = (float*)sc;      // 2 x 8192 x 512 fp32 = 33.55 MB == sizeof(sc)+sizeof(ctx)
  float* Apart = (float*)hnorm;   // 3 x 4 x 2048 x 512 fp32 = 50.3 MB <= 67.1 MB
  float* lsum  = (float*)WkT;     // 8192 fp32 = 32 KB; WkT dead after qkv; zeroed in qreduce

  // 1. prep: LN1 + mem->f16 + 4 weight transposes (one dispatch)
  prep_kernel<<<8192 + 1500 + 2048 + 512 + 512 + 2048, 256, 0, stream>>>(
      hidden, lnw1, lnb1, hnorm, mem, memh, Wq, WqT, Wk, WkT, Wv, WvT, Wo, WoT);
  // 2. fused Q(split-K x2) + K + V projections: 896 blocks (~3.5/CU)
  qkv_kernel<<<896, 256, 0, stream>>>(hnorm, WqT, Qpart, memh, WkT, bk, Kp, WvT, bv, VT);
  // 3. Q = sum partials + bq -> f16; tail blocks zero lsum
  qreduce_kernel<<<4096 + 32, 256, 0, stream>>>(Qpart, bq, Qh, lsum);
  // 4. exp-scores = exp(Q @ K^T / sqrt(A)) with mask/pad zeroing + row sums
  scores_kernel<<<dim3(12, 16, 4), 256, 0, stream>>>(Qh, Kp, sc, mask, lsum);
  // 5. ctx partials = exp-scores @ V, split-K x3 (K=512 each): 768 blocks
  gemm_nt_kernel<2><<<dim3(4, 16, 12), 256, 0, stream>>>(
      sc, (size_t)LQ_ * TMP_, TMP_, VT, (size_t)A_ * TMP_, TMP_, nullptr,
      (void*)Apart, (size_t)LQ_ * A_, (size_t)B_ * LQ_ * A_, A_, LQ_, 16, 3, 512, 1.f);
  // 6. ctx = (sum partials) / lsum -> f16
  areduce_kernel<<<4096, 256, 0, stream>>>(Apart, lsum, ctx);
  // 7. ctx_h = ctx @ Wo + bo -> reuse hnorm buffer  [8192][4096] (2048 blocks)
  gemm_nt_kernel<0><<<dim3(32, 64, 1), 256, 0, stream>>>(
      ctx, 0, A_, WoT, 0, A_, bo, (void*)hnorm, 0, 0, H_, 8192, 16, 1, 0, 1.f);
  // 8. out = hidden + g*(LN(hidden+ctx_h) - hidden)
  ln2_gate_kernel<<<8192, 256, 0, stream>>>(hidden, hnorm, lnw2, lnb2, gate, out);
}